// Round 5
// baseline (57.971 us; speedup 1.0000x reference)
//
#include <hip/hip_runtime.h>
#include <hip/hip_bf16.h>

// Problem constants
#define NBATCH 256
#define NC 273     // C_IN (K)
#define ND 273     // C_OUT (M)
#define NT 360     // T (N)

// Tiling: one block = full D (288 padded) x 120 t-columns, K-steps of 32
#define THREADS 512
#define BM 288
#define BN 128     // LDS cols (120 valid + 8 pad)
#define BNV 120
#define BK 32
#define LDK 40     // padded LDS row stride (elements) -> 80 B rows, 16B-aligned b128
#define KITERS 9   // ceil(273/32); tiles 0..7 full, tile 8 = tail

typedef __bf16 bf16_t;
typedef bf16_t bf16x4 __attribute__((ext_vector_type(4)));
typedef bf16_t bf16x8 __attribute__((ext_vector_type(8)));
typedef float  f32x4  __attribute__((ext_vector_type(4)));

// Raw barrier with NO vmcnt drain (T3/T4): LDS ops are fenced manually with
// lgkmcnt(0); outstanding global loads stay in flight across the barrier.
#define LDS_FENCE_BARRIER()                                   \
    do {                                                      \
        asm volatile("s_waitcnt lgkmcnt(0)" ::: "memory");    \
        __builtin_amdgcn_s_barrier();                         \
    } while (0)

__global__ __launch_bounds__(THREADS, 2) void subject_gemm(
    const float* __restrict__ x,        // [B, C, T]
    const int*   __restrict__ subjects, // [B]
    const float* __restrict__ w,        // [S, C, D]
    float*       __restrict__ out)      // [B, D, T]
{
    // 768 blocks = 8 XCDs x 96 slots; keep a sample's 3 t-tiles on one XCD.
    const int raw  = blockIdx.x;
    const int xcd  = raw & 7;
    const int slot = raw >> 3;          // 0..95
    const int b    = xcd * 32 + slot / 3;
    const int tt   = slot % 3;
    const int t0   = tt * BNV;
    const int s    = subjects[b];

    const float* __restrict__ xb = x + (size_t)b * NC * NT;
    const float* __restrict__ ws = w + (size_t)s * NC * ND;

    // Double-buffered LDS: 2 x (288*40 + 128*40) bf16 = 66560 B
    __shared__ __align__(16) bf16_t As[2][BM * LDK]; // [buf][d][k]
    __shared__ __align__(16) bf16_t Bs[2][BN * LDK]; // [buf][t][k]

    const int tid   = threadIdx.x;
    const int lane  = tid & 63;
    const int wid   = tid >> 6;   // 0..7
    const int wm    = wid >> 2;   // D half: 144 rows
    const int wn    = wid & 3;    // T quarter: 32 cols
    const int l16   = lane & 15;
    const int khalf = lane >> 4;  // 0..3

    // ---- staging coordinates (loop-invariant) ----
    // A: 2304 bf16x4-cells = (d 0..287) x (kq 0..7); cell i = tid + 512*j
    //    j=0..3 full, j=4 only tid<256.
    int offA[5], gA[5];
#pragma unroll
    for (int j = 0; j < 5; ++j) {
        const int i  = tid + THREADS * j;
        const int ii = (i < 2304) ? i : 2303;
        const int d  = ii % BM;
        const int kq = ii / BM;
        offA[j] = d * LDK + kq * 4;
        gA[j]   = kq * 4 * ND + d;          // + kk*ND + u*ND at load time
    }
    // B: 1024 cells = (t 0..127) x (kq 0..7); i = tid + 512*j, j=0..1
    int offB[2], gB[2];
#pragma unroll
    for (int j = 0; j < 2; ++j) {
        const int i  = tid + THREADS * j;
        const int t  = i & (BN - 1);
        const int kq = i >> 7;
        const int tc = (t < BNV) ? t : (BNV - 1);   // clamp pad cols (masked at store)
        offB[j] = t * LDK + kq * 4;
        gB[j]   = kq * 4 * NT + t0 + tc;
    }
    const bool haveJ4 = (tid < 2304 - 4 * THREADS); // tid < 256, wave-uniform

    // Depth-2 register staging buffers (tile t lives in buf t&1)
    float ra[2][5][4], rb[2][2][4];

    // Full (unmasked) loads: kk <= 224 -> c <= 255 < 273; A d<=287 stays inside
    // W[s] since 255*273+287 < 273*273 (values masked at store).
    auto loadA = [&](float (&r)[5][4], int kk) {
        const int base = kk * ND;
#pragma unroll
        for (int j = 0; j < 4; ++j)
#pragma unroll
            for (int u = 0; u < 4; ++u)
                r[j][u] = ws[base + gA[j] + u * ND];
        if (haveJ4)
#pragma unroll
            for (int u = 0; u < 4; ++u)
                r[4][u] = ws[base + gA[4] + u * ND];
    };
    auto loadB = [&](float (&r)[2][4], int kk) {
        const int base = kk * NT;
#pragma unroll
        for (int j = 0; j < 2; ++j)
#pragma unroll
            for (int u = 0; u < 4; ++u)
                r[j][u] = xb[base + gB[j] + u * NT];
    };
    // Tail (kk=256): zero A where c>=273 or d>=273 (A zeros kill B tail garbage).
    auto loadA_tail = [&](float (&r)[5][4]) {
#pragma unroll
        for (int j = 0; j < 5; ++j) {
            if (j == 4 && !haveJ4) break;
            const int i  = tid + THREADS * j;
            const int d  = i % BM;
            const int kq = i / BM;
#pragma unroll
            for (int u = 0; u < 4; ++u) {
                const int c = 256 + kq * 4 + u;
                const bool ok = (c < NC) && (d < ND);
                r[j][u] = ok ? ws[c * ND + d] : 0.f;
            }
        }
    };
    auto loadB_tail = [&](float (&r)[2][4]) {
#pragma unroll
        for (int j = 0; j < 2; ++j) {
            const int i  = tid + THREADS * j;
            const int t  = i & (BN - 1);
            const int kq = i >> 7;
            const int col = t0 + ((t < BNV) ? t : (BNV - 1));
#pragma unroll
            for (int u = 0; u < 4; ++u) {
                const int c  = 256 + kq * 4 + u;
                const int cc = (c < NC) ? c : (NC - 1);  // clamp addr; killed by A zeros
                r[j][u] = xb[cc * NT + col];
            }
        }
    };
    auto stage = [&](const float (&rA)[5][4], const float (&rB)[2][4],
                     bf16_t* __restrict__ dA, bf16_t* __restrict__ dB) {
#pragma unroll
        for (int j = 0; j < 4; ++j) {
            bf16x4 v;
#pragma unroll
            for (int u = 0; u < 4; ++u) v[u] = (bf16_t)rA[j][u];
            *(bf16x4*)&dA[offA[j]] = v;
        }
        if (haveJ4) {
            bf16x4 v;
#pragma unroll
            for (int u = 0; u < 4; ++u) v[u] = (bf16_t)rA[4][u];
            *(bf16x4*)&dA[offA[4]] = v;
        }
#pragma unroll
        for (int j = 0; j < 2; ++j) {
            bf16x4 v;
#pragma unroll
            for (int u = 0; u < 4; ++u) v[u] = (bf16_t)rB[j][u];
            *(bf16x4*)&dB[offB[j]] = v;
        }
    };

    f32x4 acc[9][2];
#pragma unroll
    for (int m = 0; m < 9; ++m)
#pragma unroll
        for (int n = 0; n < 2; ++n)
            acc[m][n] = (f32x4){0.f, 0.f, 0.f, 0.f};

    // ---- prologue: tiles 0 and 1 in flight; tile 0 staged ----
    loadA(ra[0], 0);      loadB(rb[0], 0);
    loadA(ra[1], BK);     loadB(rb[1], BK);
    stage(ra[0], rb[0], As[0], Bs[0]);   // counted vmcnt: waits tile0, tile1 stays in flight
    LDS_FENCE_BARRIER();

#pragma unroll
    for (int it = 0; it < KITERS; ++it) {
        const int cur = it & 1;
        const bf16_t* __restrict__ Ac = As[cur];
        const bf16_t* __restrict__ Bc = Bs[cur];

        // 1) fragment ds_reads from current buffer (before any ds_write this iter)
        bf16x8 af[9], bfr[2];
#pragma unroll
        for (int n = 0; n < 2; ++n)
            bfr[n] = *(const bf16x8*)&Bc[(wn * 32 + n * 16 + l16) * LDK + khalf * 8];
#pragma unroll
        for (int m = 0; m < 9; ++m)
            af[m] = *(const bf16x8*)&Ac[(wm * 144 + m * 16 + l16) * LDK + khalf * 8];

        // 2) issue global loads for tile it+2 (stay in flight across the barrier)
        if (it + 2 <= KITERS - 2) {
            loadA(ra[cur], (it + 2) * BK);
            loadB(rb[cur], (it + 2) * BK);
        } else if (it + 2 == KITERS - 1) {
            loadA_tail(ra[cur]);
            loadB_tail(rb[cur]);
        }

        // 3) stage tile it+1 -> LDS[cur^1]; counted vmcnt waits ONLY for tile it+1's
        //    loads (issued a full iteration ago); tile it+2's remain outstanding
        if (it + 1 < KITERS)
            stage(ra[cur ^ 1], rb[cur ^ 1], As[cur ^ 1], Bs[cur ^ 1]);

        // 4) fence LDS (reads of step 1 + writes of step 3) and barrier — NO vmcnt drain
        if (it + 1 < KITERS)
            LDS_FENCE_BARRIER();

        // 5) MFMA (register-only; overlaps next iter's issue window after unroll)
#pragma unroll
        for (int m = 0; m < 9; ++m)
#pragma unroll
            for (int n = 0; n < 2; ++n)
                acc[m][n] = __builtin_amdgcn_mfma_f32_16x16x32_bf16(af[m], bfr[n], acc[m][n], 0, 0, 0);
    }

    // Epilogue: C/D layout col(t)=lane&15, row(d)=(lane>>4)*4+reg (verified R1-R4)
    float* __restrict__ ob = out + (size_t)b * ND * NT;
#pragma unroll
    for (int m = 0; m < 9; ++m) {
#pragma unroll
        for (int n = 0; n < 2; ++n) {
            const int tc = wn * 32 + n * 16 + l16;
            const int gt = t0 + tc;
#pragma unroll
            for (int rg = 0; rg < 4; ++rg) {
                const int d = wm * 144 + m * 16 + khalf * 4 + rg;
                if (d < ND && tc < BNV)
                    ob[(size_t)d * NT + gt] = acc[m][n][rg];
            }
        }
    }
}

extern "C" void kernel_launch(void* const* d_in, const int* in_sizes, int n_in,
                              void* d_out, int out_size, void* d_ws, size_t ws_size,
                              hipStream_t stream) {
    const float* x        = (const float*)d_in[0];
    const int*   subjects = (const int*)d_in[1];
    const float* w        = (const float*)d_in[2];
    float*       out      = (float*)d_out;

    const int nblocks = NBATCH * 3; // 768 = 8 XCDs * 96
    subject_gemm<<<nblocks, THREADS, 0, stream>>>(x, subjects, w, out);
}